// Round 3
// baseline (462.966 us; speedup 1.0000x reference)
//
#include <hip/hip_runtime.h>
#include <hip/hip_bf16.h>

// Problem constants (from reference setup_inputs): B=60, T=4, K=100, 1M docs.
#define T_DIM 4
#define K_DIM 100
#define NPER 400          // T*K entries per row
#define NDOCS 1000000
#define FILL_BLOCK 256
#define FILL_PER_THREAD 16
#define FILL_CHUNK (FILL_BLOCK * FILL_PER_THREAD)               // 4096
#define BLOCKS_PER_ROW ((NDOCS + FILL_CHUNK - 1) / FILL_CHUNK)  // 245 (tail=576)

// Native vector type for nontemporal stores (__builtin_nontemporal_store
// rejects HIP_vector_type<int,4>*; needs scalar or ext_vector_type).
typedef int ivec4 __attribute__((ext_vector_type(4)));

// -------- Kernel 1: per-row preprocessing (tiny) ------------------------
// Produces, per row b:
//   wsA[b*NPER + i]    = S[i] - i  (S = unique nonzero doc ids, ascending), i < nnz
//   wsHead[b*NPER + i] = i-th doc in (-score, id) order, i < nnz
//   wsNnz[b]           = nnz
//   out_pos[b]         = head[pos_positions[b]]   (positive_idx output)
__global__ __launch_bounds__(512) void rrf_prep_kernel(
    const int* __restrict__ idx, const float* __restrict__ rnk,
    const float* __restrict__ weight, const int* __restrict__ pos,
    int* __restrict__ wsA, int* __restrict__ wsHead, int* __restrict__ wsNnz,
    int* __restrict__ out_pos)
{
  const int b = blockIdx.x;
  const int tid = threadIdx.x;

  __shared__ int   ids[NPER];
  __shared__ float sc[NPER];
  __shared__ int   sid[NPER];
  __shared__ float ssc[NPER];
  __shared__ int   scan[512];
  __shared__ int   uid[NPER];
  __shared__ float usc[NPER];
  __shared__ int   head[NPER];
  __shared__ int   s_nnz;

  // Load ids + compute rrf scores: w_t / (60 + rank)
  if (tid < NPER) {
    ids[tid] = idx[b * NPER + tid];
    sc[tid]  = weight[tid / K_DIM] / (60.0f + rnk[b * NPER + tid]);
  }
  __syncthreads();

  // Rank-sort by (id, original position) -> groups duplicates adjacently,
  // duplicate scores kept in original-position order for summation.
  if (tid < NPER) {
    const int myid = ids[tid];
    int r = 0;
    for (int j = 0; j < NPER; ++j) {
      const int oj = ids[j];
      r += (oj < myid) || (oj == myid && j < tid);
    }
    sid[r] = myid;
    ssc[r] = sc[tid];
  }
  __syncthreads();

  // Leaders sum their duplicate run (in original-position order).
  int isLeader = 0;
  float mysum = 0.0f;
  if (tid < NPER) {
    isLeader = (tid == 0) || (sid[tid] != sid[tid - 1]);
    if (isLeader) {
      mysum = ssc[tid];
      for (int k = tid + 1; k < NPER && sid[k] == sid[tid]; ++k) mysum += ssc[k];
    }
  }
  scan[tid] = isLeader;
  __syncthreads();
  // Hillis-Steele inclusive scan over 512 slots (flags 0 beyond NPER).
  for (int off = 1; off < 512; off <<= 1) {
    int v = scan[tid];
    if (tid >= off) v += scan[tid - off];
    __syncthreads();
    scan[tid] = v;
    __syncthreads();
  }
  if (isLeader) {
    const int u = scan[tid] - 1;   // compacted slot; ascending id order preserved
    uid[u] = sid[tid];
    usc[u] = mysum;
  }
  if (tid == 0) s_nnz = scan[511];
  __syncthreads();
  const int nnz = s_nnz;

  // Rank-sort uniques by (-score, id asc) == stable argsort(-fused) order.
  if (tid < nnz) {
    const float si = usc[tid];
    const int   ii = uid[tid];
    int r2 = 0;
    for (int j = 0; j < nnz; ++j) {
      const float sj = usc[j];
      r2 += (sj > si) || (sj == si && uid[j] < ii);
    }
    head[r2] = ii;
  }
  __syncthreads();

  if (tid < nnz) {
    wsA[b * NPER + tid]    = uid[tid] - tid;  // A[i] = S[i]-i, non-decreasing
    wsHead[b * NPER + tid] = head[tid];
  }
  if (tid == 0) {
    wsNnz[b]   = nnz;
    out_pos[b] = head[pos[b]];   // pos in [0,5), nnz >= ~396 always
  }
}

// -------- Kernel 2: write order[B, NDOCS] (the 240 MB store) ------------
// order[p] = head[p] for p < nnz; else z = p - nnz, doc = z + count{A[i] <= z}.
// 16 outputs/thread: one binary search seeds j, then linear advance over 16
// consecutive z (expected advances ~0.006/thread). 4x int4 nontemporal stores.
__global__ __launch_bounds__(FILL_BLOCK) void rrf_fill_kernel(
    const int* __restrict__ wsA, const int* __restrict__ wsHead,
    const int* __restrict__ wsNnz, int* __restrict__ out)
{
  const int row   = blockIdx.x / BLOCKS_PER_ROW;
  const int chunk = blockIdx.x % BLOCKS_PER_ROW;
  const int tid   = threadIdx.x;

  __shared__ int A[NPER];
  __shared__ int H[NPER];
  __shared__ int s_nnz;

  // A needed by every block; H only by chunk 0 (positions < nnz ~ 400).
  for (int i = tid; i < NPER; i += FILL_BLOCK)
    A[i] = wsA[row * NPER + i];          // entries >= nnz are garbage, never read
  if (chunk == 0)
    for (int i = tid; i < NPER; i += FILL_BLOCK)
      H[i] = wsHead[row * NPER + i];
  if (tid == 0) s_nnz = wsNnz[row];
  __syncthreads();
  const int nnz = s_nnz;

  const int lp0 = chunk * FILL_CHUNK + tid * FILL_PER_THREAD;
  if (lp0 >= NDOCS) return;  // tail chunk: 576 = 36*16, all-or-nothing per thread

  int v[FILL_PER_THREAD];
  if (lp0 >= nnz) {
    // Fast path (all blocks except part of chunk 0 of each row).
    int z = lp0 - nnz;
    int lo = 0, hi = nnz;
    while (lo < hi) { const int mid = (lo + hi) >> 1; if (A[mid] <= z) lo = mid + 1; else hi = mid; }
    int j = lo;                          // count{A[i] <= z}
    v[0] = z + j;
#pragma unroll
    for (int k = 1; k < FILL_PER_THREAD; ++k) {
      ++z;
      while (j < nnz && A[j] <= z) ++j;
      v[k] = z + j;
    }
  } else {
    // Slow path: only ~25 threads of chunk 0 in each row.
#pragma unroll
    for (int k = 0; k < FILL_PER_THREAD; ++k) {
      const int p = lp0 + k;
      if (p < nnz) v[k] = H[p];
      else {
        const int z = p - nnz;
        int lo = 0, hi = nnz;
        while (lo < hi) { const int mid = (lo + hi) >> 1; if (A[mid] <= z) lo = mid + 1; else hi = mid; }
        v[k] = z + lo;
      }
    }
  }

  // 4x coalesced 16B nontemporal stores; base is 64B-aligned
  // (row*NDOCS*4 = 4e6 B multiple, lp0*4 multiple of 64).
  ivec4* o = reinterpret_cast<ivec4*>(out + (long long)row * NDOCS + lp0);
#pragma unroll
  for (int q = 0; q < 4; ++q) {
    ivec4 pk;
    pk.x = v[4 * q + 0]; pk.y = v[4 * q + 1];
    pk.z = v[4 * q + 2]; pk.w = v[4 * q + 3];
    __builtin_nontemporal_store(pk, o + q);
  }
}

extern "C" void kernel_launch(void* const* d_in, const int* in_sizes, int n_in,
                              void* d_out, int out_size, void* d_ws, size_t ws_size,
                              hipStream_t stream) {
  const int*   idx    = (const int*)d_in[0];    // [B,T,K] int32
  const float* rnk    = (const float*)d_in[1];  // [B,T,K] f32
  const float* weight = (const float*)d_in[2];  // [T] f32
  const int*   pos    = (const int*)d_in[3];    // [B] int32
  const int B = in_sizes[3];                    // 60

  int* out = (int*)d_out;                       // order[B*NDOCS] ++ positive_idx[B], int32
  int* ws  = (int*)d_ws;
  int* wsA    = ws;                             // B*NPER ints
  int* wsHead = ws + (size_t)B * NPER;          // B*NPER ints
  int* wsNnz  = ws + (size_t)2 * B * NPER;      // B ints   (~192 KB total)

  rrf_prep_kernel<<<B, 512, 0, stream>>>(idx, rnk, weight, pos,
                                         wsA, wsHead, wsNnz,
                                         out + (size_t)B * NDOCS);
  rrf_fill_kernel<<<B * BLOCKS_PER_ROW, FILL_BLOCK, 0, stream>>>(wsA, wsHead, wsNnz, out);
}

// Round 4
// 293.673 us; speedup vs baseline: 1.5765x; 1.5765x over previous
//
#include <hip/hip_runtime.h>
#include <hip/hip_bf16.h>

// Problem constants (from reference setup_inputs): B=60, T=4, K=100, 1M docs.
#define T_DIM 4
#define K_DIM 100
#define NPER 400          // T*K entries per row
#define NDOCS 1000000
#define FILL_BLOCK 256
#define FILL_PER_THREAD 16
#define FILL_CHUNK (FILL_BLOCK * FILL_PER_THREAD)               // 4096 elements
#define BLOCKS_PER_ROW ((NDOCS + FILL_CHUNK - 1) / FILL_CHUNK)  // 245 (tail=576)

// Native vector type for nontemporal stores (__builtin_nontemporal_store
// rejects HIP_vector_type<int,4>*; needs scalar or ext_vector_type).
typedef int ivec4 __attribute__((ext_vector_type(4)));

// -------- Kernel 1: per-row preprocessing (tiny) ------------------------
// Produces, per row b:
//   wsA[b*NPER + i]    = S[i] - i  (S = unique nonzero doc ids, ascending), i < nnz
//   wsHead[b*NPER + i] = i-th doc in (-score, id) order, i < nnz
//   wsNnz[b]           = nnz
//   out_pos[b]         = head[pos_positions[b]]   (positive_idx output)
__global__ __launch_bounds__(512) void rrf_prep_kernel(
    const int* __restrict__ idx, const float* __restrict__ rnk,
    const float* __restrict__ weight, const int* __restrict__ pos,
    int* __restrict__ wsA, int* __restrict__ wsHead, int* __restrict__ wsNnz,
    int* __restrict__ out_pos)
{
  const int b = blockIdx.x;
  const int tid = threadIdx.x;

  __shared__ int   ids[NPER];
  __shared__ float sc[NPER];
  __shared__ int   sid[NPER];
  __shared__ float ssc[NPER];
  __shared__ int   scan[512];
  __shared__ int   uid[NPER];
  __shared__ float usc[NPER];
  __shared__ int   head[NPER];
  __shared__ int   s_nnz;

  // Load ids + compute rrf scores: w_t / (60 + rank)
  if (tid < NPER) {
    ids[tid] = idx[b * NPER + tid];
    sc[tid]  = weight[tid / K_DIM] / (60.0f + rnk[b * NPER + tid]);
  }
  __syncthreads();

  // Rank-sort by (id, original position) -> groups duplicates adjacently,
  // duplicate scores kept in original-position order for summation.
  if (tid < NPER) {
    const int myid = ids[tid];
    int r = 0;
    for (int j = 0; j < NPER; ++j) {
      const int oj = ids[j];
      r += (oj < myid) || (oj == myid && j < tid);
    }
    sid[r] = myid;
    ssc[r] = sc[tid];
  }
  __syncthreads();

  // Leaders sum their duplicate run (in original-position order).
  int isLeader = 0;
  float mysum = 0.0f;
  if (tid < NPER) {
    isLeader = (tid == 0) || (sid[tid] != sid[tid - 1]);
    if (isLeader) {
      mysum = ssc[tid];
      for (int k = tid + 1; k < NPER && sid[k] == sid[tid]; ++k) mysum += ssc[k];
    }
  }
  scan[tid] = isLeader;
  __syncthreads();
  // Hillis-Steele inclusive scan over 512 slots (flags 0 beyond NPER).
  for (int off = 1; off < 512; off <<= 1) {
    int v = scan[tid];
    if (tid >= off) v += scan[tid - off];
    __syncthreads();
    scan[tid] = v;
    __syncthreads();
  }
  if (isLeader) {
    const int u = scan[tid] - 1;   // compacted slot; ascending id order preserved
    uid[u] = sid[tid];
    usc[u] = mysum;
  }
  if (tid == 0) s_nnz = scan[511];
  __syncthreads();
  const int nnz = s_nnz;

  // Rank-sort uniques by (-score, id asc) == stable argsort(-fused) order.
  if (tid < nnz) {
    const float si = usc[tid];
    const int   ii = uid[tid];
    int r2 = 0;
    for (int j = 0; j < nnz; ++j) {
      const float sj = usc[j];
      r2 += (sj > si) || (sj == si && uid[j] < ii);
    }
    head[r2] = ii;
  }
  __syncthreads();

  if (tid < nnz) {
    wsA[b * NPER + tid]    = uid[tid] - tid;  // A[i] = S[i]-i, non-decreasing
    wsHead[b * NPER + tid] = head[tid];
  }
  if (tid == 0) {
    wsNnz[b]   = nnz;
    out_pos[b] = head[pos[b]];   // pos in [0,5), nnz >= ~396 always
  }
}

// -------- Kernel 2: write order[B, NDOCS] (the 240 MB store) ------------
// order[p] = head[p] for p < nnz; else z = p - nnz, doc = z + count{A[i] <= z}.
// Block-strided int4 layout: thread t's q-th int4 sits at int4-index
// chunk*1024 + q*256 + t, so each store instruction is a contiguous
// 4 KB/block (16 B/lane) — full-line coverage, nontemporal-safe.
// One binary search seeds j; linear advance across the 4 groups
// (groups 1024 elements apart; expected ~0.4 advances/jump, <=nnz total).
__global__ __launch_bounds__(FILL_BLOCK) void rrf_fill_kernel(
    const int* __restrict__ wsA, const int* __restrict__ wsHead,
    const int* __restrict__ wsNnz, int* __restrict__ out)
{
  const int row   = blockIdx.x / BLOCKS_PER_ROW;
  const int chunk = blockIdx.x % BLOCKS_PER_ROW;
  const int tid   = threadIdx.x;

  __shared__ int A[NPER];
  __shared__ int H[NPER];
  __shared__ int s_nnz;

  // A needed by every block; H only by chunk 0 (positions < nnz ~ 400).
  for (int i = tid; i < NPER; i += FILL_BLOCK)
    A[i] = wsA[row * NPER + i];          // entries >= nnz are garbage, never read
  if (chunk == 0)
    for (int i = tid; i < NPER; i += FILL_BLOCK)
      H[i] = wsHead[row * NPER + i];
  if (tid == 0) s_nnz = wsNnz[row];
  __syncthreads();
  const int nnz = s_nnz;

  const int chunkbase = chunk * FILL_CHUNK;
  const long long rowbase = (long long)row * NDOCS;

  int j = 0;
  bool jvalid = false;
#pragma unroll
  for (int q = 0; q < 4; ++q) {
    const int p0 = chunkbase + q * 1024 + tid * 4;   // 4 consecutive elements
    if (p0 < NDOCS) {                                // tail: 576 = 144 int4s, q=0 only
      ivec4 pk;
      if (p0 >= nnz) {
        // Fast path (everything except ~100 threads of chunk 0, q=0).
        int z = p0 - nnz;
        if (!jvalid) {
          int lo = 0, hi = nnz;
          while (lo < hi) { const int mid = (lo + hi) >> 1; if (A[mid] <= z) lo = mid + 1; else hi = mid; }
          j = lo;                        // count{A[i] <= z}
          jvalid = true;
        } else {
          while (j < nnz && A[j] <= z) ++j;
        }
        pk.x = z + j;
        ++z; while (j < nnz && A[j] <= z) ++j; pk.y = z + j;
        ++z; while (j < nnz && A[j] <= z) ++j; pk.z = z + j;
        ++z; while (j < nnz && A[j] <= z) ++j; pk.w = z + j;
      } else {
        // Slow path: only chunk 0 / q=0 / low threads.
        int vv[4];
#pragma unroll
        for (int k = 0; k < 4; ++k) {
          const int p = p0 + k;
          if (p < nnz) vv[k] = H[p];
          else {
            const int z = p - nnz;
            int lo = 0, hi = nnz;
            while (lo < hi) { const int mid = (lo + hi) >> 1; if (A[mid] <= z) lo = mid + 1; else hi = mid; }
            vv[k] = z + lo;
          }
        }
        pk.x = vv[0]; pk.y = vv[1]; pk.z = vv[2]; pk.w = vv[3];
      }
      // Coalesced contiguous 16B/lane nontemporal store (64B-aligned base).
      __builtin_nontemporal_store(pk, reinterpret_cast<ivec4*>(out + rowbase + p0));
    }
  }
}

extern "C" void kernel_launch(void* const* d_in, const int* in_sizes, int n_in,
                              void* d_out, int out_size, void* d_ws, size_t ws_size,
                              hipStream_t stream) {
  const int*   idx    = (const int*)d_in[0];    // [B,T,K] int32
  const float* rnk    = (const float*)d_in[1];  // [B,T,K] f32
  const float* weight = (const float*)d_in[2];  // [T] f32
  const int*   pos    = (const int*)d_in[3];    // [B] int32
  const int B = in_sizes[3];                    // 60

  int* out = (int*)d_out;                       // order[B*NDOCS] ++ positive_idx[B], int32
  int* ws  = (int*)d_ws;
  int* wsA    = ws;                             // B*NPER ints
  int* wsHead = ws + (size_t)B * NPER;          // B*NPER ints
  int* wsNnz  = ws + (size_t)2 * B * NPER;      // B ints   (~192 KB total)

  rrf_prep_kernel<<<B, 512, 0, stream>>>(idx, rnk, weight, pos,
                                         wsA, wsHead, wsNnz,
                                         out + (size_t)B * NDOCS);
  rrf_fill_kernel<<<B * BLOCKS_PER_ROW, FILL_BLOCK, 0, stream>>>(wsA, wsHead, wsNnz, out);
}

// Round 5
// 287.179 us; speedup vs baseline: 1.6121x; 1.0226x over previous
//
#include <hip/hip_runtime.h>
#include <hip/hip_bf16.h>

// Problem constants (from reference setup_inputs): B=60, T=4, K=100, 1M docs.
#define T_DIM 4
#define K_DIM 100
#define NPER 400          // T*K entries per row
#define NDOCS 1000000
#define FILL_BLOCK 256
#define FILL_PER_THREAD 16
#define FILL_CHUNK (FILL_BLOCK * FILL_PER_THREAD)               // 4096 elements
#define BLOCKS_PER_ROW ((NDOCS + FILL_CHUNK - 1) / FILL_CHUNK)  // 245 (tail=576)

// -------- Kernel 1: per-row preprocessing (tiny) ------------------------
// Produces, per row b:
//   wsA[b*NPER + i]    = S[i] - i  (S = unique nonzero doc ids, ascending), i < nnz
//   wsHead[b*NPER + i] = i-th doc in (-score, id) order, i < nnz
//   wsNnz[b]           = nnz
//   out_pos[b]         = head[pos_positions[b]]   (positive_idx output)
__global__ __launch_bounds__(512) void rrf_prep_kernel(
    const int* __restrict__ idx, const float* __restrict__ rnk,
    const float* __restrict__ weight, const int* __restrict__ pos,
    int* __restrict__ wsA, int* __restrict__ wsHead, int* __restrict__ wsNnz,
    int* __restrict__ out_pos)
{
  const int b = blockIdx.x;
  const int tid = threadIdx.x;
  const int lane = tid & 63, wave = tid >> 6;

  __shared__ int   ids[NPER];
  __shared__ float sc[NPER];
  __shared__ int   sid[NPER];
  __shared__ float ssc[NPER];
  __shared__ int   uid[NPER];
  __shared__ float usc[NPER];
  __shared__ int   head[NPER];
  __shared__ int   wsum[8];

  // Load ids + compute rrf scores: w_t / (60 + rank)
  if (tid < NPER) {
    ids[tid] = idx[b * NPER + tid];
    sc[tid]  = weight[tid / K_DIM] / (60.0f + rnk[b * NPER + tid]);
  }
  __syncthreads();

  // Rank-sort by (id, original position) -> groups duplicates adjacently,
  // duplicate scores kept in original-position order for summation.
  if (tid < NPER) {
    const int myid = ids[tid];
    int r = 0;
    for (int j = 0; j < NPER; ++j) {
      const int oj = ids[j];
      r += (oj < myid) || (oj == myid && j < tid);
    }
    sid[r] = myid;
    ssc[r] = sc[tid];
  }
  __syncthreads();

  // Leaders sum their duplicate run (in original-position order).
  int isLeader = 0;
  float mysum = 0.0f;
  if (tid < NPER) {
    isLeader = (tid == 0) || (sid[tid] != sid[tid - 1]);
    if (isLeader) {
      mysum = ssc[tid];
      for (int k = tid + 1; k < NPER && sid[k] == sid[tid]; ++k) mysum += ssc[k];
    }
  }

  // Inclusive scan of isLeader over 512 threads: shuffle wave scan + combine.
  int val = isLeader;
#pragma unroll
  for (int off = 1; off < 64; off <<= 1) {
    int n = __shfl_up(val, off, 64);
    if (lane >= off) val += n;
  }
  if (lane == 63) wsum[wave] = val;
  __syncthreads();
  if (wave == 0 && lane < 8) {
    int wv = wsum[lane];
#pragma unroll
    for (int off = 1; off < 8; off <<= 1) {
      int n = __shfl_up(wv, off, 8);
      if ((lane & 7) >= off) wv += n;
    }
    wsum[lane] = wv;     // inclusive per-wave totals
  }
  __syncthreads();
  const int incl = val + (wave > 0 ? wsum[wave - 1] : 0);
  const int nnz  = wsum[7];

  if (isLeader) {
    const int u = incl - 1;        // compacted slot; ascending id order preserved
    uid[u] = sid[tid];
    usc[u] = mysum;
  }
  __syncthreads();

  // Rank-sort uniques by (-score, id asc) == stable argsort(-fused) order.
  if (tid < nnz) {
    const float si = usc[tid];
    const int   ii = uid[tid];
    int r2 = 0;
    for (int j = 0; j < nnz; ++j) {
      const float sj = usc[j];
      r2 += (sj > si) || (sj == si && uid[j] < ii);
    }
    head[r2] = ii;
  }
  __syncthreads();

  if (tid < nnz) {
    wsA[b * NPER + tid]    = uid[tid] - tid;  // A[i] = S[i]-i, non-decreasing
    wsHead[b * NPER + tid] = head[tid];
  }
  if (tid == 0) {
    wsNnz[b]   = nnz;
    out_pos[b] = head[pos[b]];   // pos in [0,5), nnz >= ~396 always
  }
}

// -------- Kernel 2: write order[B, NDOCS] (the 240 MB store) ------------
// order[p] = head[p] for p < nnz; else z = p - nnz, doc = z + count{A[i] <= z}.
// Block-strided int4 layout: thread t's q-th int4 sits at int4-index
// chunk*1024 + q*256 + t -> each store instruction covers a contiguous
// 4 KB/block (16 B/lane), full-line coverage.
// Normal (allocating) stores: 240 MB output fits the 256 MiB L3; writeback
// drains after kernel end, overlapped with subsequent stream work.
// Each group does an INDEPENDENT binary search (ILP across the 4 groups,
// no carried-j serial LDS chain). Generic path only for chunk 0 (head
// positions) and the tail chunk — 120 of 14,700 blocks.
__global__ __launch_bounds__(FILL_BLOCK) void rrf_fill_kernel(
    const int* __restrict__ wsA, const int* __restrict__ wsHead,
    const int* __restrict__ wsNnz, int* __restrict__ out)
{
  const int row   = blockIdx.x / BLOCKS_PER_ROW;
  const int chunk = blockIdx.x % BLOCKS_PER_ROW;
  const int tid   = threadIdx.x;

  __shared__ int A[NPER];
  __shared__ int H[NPER];
  __shared__ int s_nnz;

  // A needed by every block; H only by chunk 0 (positions < nnz ~ 400).
  for (int i = tid; i < NPER; i += FILL_BLOCK)
    A[i] = wsA[row * NPER + i];          // entries >= nnz are garbage, never read
  if (chunk == 0)
    for (int i = tid; i < NPER; i += FILL_BLOCK)
      H[i] = wsHead[row * NPER + i];
  if (tid == 0) s_nnz = wsNnz[row];
  __syncthreads();
  const int nnz = s_nnz;

  const int chunkbase = chunk * FILL_CHUNK;
  int* outrow = out + (long long)row * NDOCS;

  if (chunkbase >= nnz && chunk + 1 < BLOCKS_PER_ROW) {
    // Fast path: full chunk, pure zero-tail (all chunks except 0 and tail).
#pragma unroll
    for (int q = 0; q < 4; ++q) {
      const int p0 = chunkbase + q * 1024 + tid * 4;
      int z = p0 - nnz;
      int lo = 0, hi = nnz;
      while (lo < hi) { const int mid = (lo + hi) >> 1; if (A[mid] <= z) lo = mid + 1; else hi = mid; }
      int j = lo;                        // count{A[i] <= z}
      int4 pk;
      pk.x = z + j;
      ++z; while (j < nnz && A[j] <= z) ++j; pk.y = z + j;
      ++z; while (j < nnz && A[j] <= z) ++j; pk.z = z + j;
      ++z; while (j < nnz && A[j] <= z) ++j; pk.w = z + j;
      *reinterpret_cast<int4*>(outrow + p0) = pk;   // contiguous 16B/lane
    }
  } else {
    // Generic path: chunk 0 (head region) and the 576-element tail chunk.
#pragma unroll
    for (int q = 0; q < 4; ++q) {
      const int p0 = chunkbase + q * 1024 + tid * 4;
      if (p0 >= NDOCS) continue;         // tail: 576 = 144 int4s, all-or-none
      int vv[4];
#pragma unroll
      for (int k = 0; k < 4; ++k) {
        const int p = p0 + k;
        if (p < nnz) vv[k] = H[p];
        else {
          const int z = p - nnz;
          int lo = 0, hi = nnz;
          while (lo < hi) { const int mid = (lo + hi) >> 1; if (A[mid] <= z) lo = mid + 1; else hi = mid; }
          vv[k] = z + lo;
        }
      }
      *reinterpret_cast<int4*>(outrow + p0) = make_int4(vv[0], vv[1], vv[2], vv[3]);
    }
  }
}

extern "C" void kernel_launch(void* const* d_in, const int* in_sizes, int n_in,
                              void* d_out, int out_size, void* d_ws, size_t ws_size,
                              hipStream_t stream) {
  const int*   idx    = (const int*)d_in[0];    // [B,T,K] int32
  const float* rnk    = (const float*)d_in[1];  // [B,T,K] f32
  const float* weight = (const float*)d_in[2];  // [T] f32
  const int*   pos    = (const int*)d_in[3];    // [B] int32
  const int B = in_sizes[3];                    // 60

  int* out = (int*)d_out;                       // order[B*NDOCS] ++ positive_idx[B], int32
  int* ws  = (int*)d_ws;
  int* wsA    = ws;                             // B*NPER ints
  int* wsHead = ws + (size_t)B * NPER;          // B*NPER ints
  int* wsNnz  = ws + (size_t)2 * B * NPER;      // B ints   (~192 KB total)

  rrf_prep_kernel<<<B, 512, 0, stream>>>(idx, rnk, weight, pos,
                                         wsA, wsHead, wsNnz,
                                         out + (size_t)B * NDOCS);
  rrf_fill_kernel<<<B * BLOCKS_PER_ROW, FILL_BLOCK, 0, stream>>>(wsA, wsHead, wsNnz, out);
}